// Round 1
// baseline (903.276 us; speedup 1.0000x reference)
//
#include <hip/hip_runtime.h>
#include <hip/hip_bf16.h>
#include <math.h>

#define NSEG 2048
#define HDIM 256   // H (= K for both GEMMs)
#define HGATE 128  // H/2
#define BM 128
#define BK 64

typedef __attribute__((ext_vector_type(4))) float f32x4;
typedef __attribute__((ext_vector_type(8))) short short8;

static __device__ __forceinline__ unsigned short f2bf(float f) {
  unsigned u = __float_as_uint(f);
  u += 0x7FFFu + ((u >> 16) & 1u);
  return (unsigned short)(u >> 16);
}

// ---------------------------------------------------------------------------
// Weight conversion: fp32 [K][N] -> bf16 transposed [N][K] in workspace.
// gate_w1: [256][128] -> w1t [128][256]; feat_w: [256][256] -> fwt [256][256]
// ---------------------------------------------------------------------------
__global__ void convert_weights_kernel(const float* __restrict__ w1,
                                       const float* __restrict__ fw,
                                       unsigned short* __restrict__ w1t,
                                       unsigned short* __restrict__ fwt) {
  int i = blockIdx.x * 256 + threadIdx.x;
  if (i < HDIM * HGATE) {
    int k = i >> 7, n = i & (HGATE - 1);
    w1t[n * HDIM + k] = f2bf(w1[i]);
  } else if (i < HDIM * HGATE + HDIM * HDIM) {
    int j = i - HDIM * HGATE;
    int k = j >> 8, n = j & (HDIM - 1);
    fwt[n * HDIM + k] = f2bf(fw[j]);
  }
}

// ---------------------------------------------------------------------------
// Shared GEMM core: C[128 x 128] tile = x[rowBase:rowBase+128, 0:256] (fp32,
// converted to bf16 in staging) @ wt[nBase:nBase+128, 0:256]^T (bf16, [N][K]).
// 4 waves in 2x2; wave tile 64x64 = 4x4 fragments of 16x16, K-loop 4 x BK=64.
// LDS tiles XOR-swizzled: 16B-chunk index ^= (row & 7).
// ---------------------------------------------------------------------------
__device__ __forceinline__ void gemm_core(const float* __restrict__ x,
                                          const unsigned short* __restrict__ wt,
                                          int rowBase, int nBase, int Nrows,
                                          unsigned short* As, unsigned short* Bs,
                                          f32x4 acc[4][4]) {
  const int tid = threadIdx.x;
  const int lane = tid & 63;
  const int wid = tid >> 6;
  const int wm = wid >> 1, wn = wid & 1;
  const int l16 = lane & 15, lq = lane >> 4;

#pragma unroll
  for (int kt = 0; kt < HDIM / BK; ++kt) {
    const int k0 = kt * BK;
    __syncthreads();
    // stage A: 128 rows x 64 fp32 -> bf16, 1024 chunks of 16B, 4 per thread
#pragma unroll
    for (int it = 0; it < 4; ++it) {
      int c = tid + it * 256;
      int r = c >> 3, c8 = c & 7;
      int grow = rowBase + r;
      if (grow >= Nrows) grow = Nrows - 1;  // clamp: avoid OOB; masked later
      const float* src = x + (size_t)grow * HDIM + k0 + c8 * 8;
      float4 v0 = *(const float4*)src;
      float4 v1 = *(const float4*)(src + 4);
      union { unsigned short s[8]; uint4 q; } p;
      p.s[0] = f2bf(v0.x); p.s[1] = f2bf(v0.y); p.s[2] = f2bf(v0.z); p.s[3] = f2bf(v0.w);
      p.s[4] = f2bf(v1.x); p.s[5] = f2bf(v1.y); p.s[6] = f2bf(v1.z); p.s[7] = f2bf(v1.w);
      *(uint4*)((char*)As + r * 128 + ((c8 ^ (r & 7)) << 4)) = p.q;
    }
    // stage B: 128 n-rows x 64 bf16 (already bf16, [N][K] layout)
#pragma unroll
    for (int it = 0; it < 4; ++it) {
      int c = tid + it * 256;
      int r = c >> 3, c8 = c & 7;
      const unsigned short* src = wt + (size_t)(nBase + r) * HDIM + k0 + c8 * 8;
      *(uint4*)((char*)Bs + r * 128 + ((c8 ^ (r & 7)) << 4)) = *(const uint4*)src;
    }
    __syncthreads();
#pragma unroll
    for (int kk = 0; kk < 2; ++kk) {
      short8 a[4], b[4];
#pragma unroll
      for (int m = 0; m < 4; ++m) {
        int row = wm * 64 + m * 16 + l16;
        int ck = kk * 4 + lq;
        a[m] = *(const short8*)((const char*)As + row * 128 + ((ck ^ (row & 7)) << 4));
      }
#pragma unroll
      for (int n = 0; n < 4; ++n) {
        int row = wn * 64 + n * 16 + l16;
        int ck = kk * 4 + lq;
        b[n] = *(const short8*)((const char*)Bs + row * 128 + ((ck ^ (row & 7)) << 4));
      }
#pragma unroll
      for (int m = 0; m < 4; ++m)
#pragma unroll
        for (int n = 0; n < 4; ++n)
          acc[m][n] = __builtin_amdgcn_mfma_f32_16x16x32_bf16(a[m], b[n], acc[m][n], 0, 0, 0);
    }
  }
}

// ---------------------------------------------------------------------------
// Pass 1: scores[i] = b2 + sum_j relu(x_i . W1[:,j] + b1[j]) * w2[j]
// ---------------------------------------------------------------------------
__global__ __launch_bounds__(256) void gate_kernel(
    const float* __restrict__ x, const unsigned short* __restrict__ w1t,
    const float* __restrict__ gb1, const float* __restrict__ gw2,
    const float* __restrict__ gb2, float* __restrict__ scores, int Nrows) {
  __shared__ unsigned short As[BM * BK];
  __shared__ unsigned short Bs[HGATE * BK];
  __shared__ float spart[2][BM];

  const int rowBase = blockIdx.x * BM;
  const int tid = threadIdx.x;
  const int lane = tid & 63;
  const int wid = tid >> 6;
  const int wm = wid >> 1, wn = wid & 1;
  const int l16 = lane & 15, lq = lane >> 4;

  f32x4 acc[4][4] = {};
  gemm_core(x, w1t, rowBase, 0, Nrows, As, Bs, acc);

  float b1v[4], w2v[4];
#pragma unroll
  for (int n = 0; n < 4; ++n) {
    int col = wn * 64 + n * 16 + l16;
    b1v[n] = gb1[col];
    w2v[n] = gw2[col];
  }
#pragma unroll
  for (int m = 0; m < 4; ++m) {
#pragma unroll
    for (int r = 0; r < 4; ++r) {
      float s = 0.f;
#pragma unroll
      for (int n = 0; n < 4; ++n)
        s += fmaxf(acc[m][n][r] + b1v[n], 0.f) * w2v[n];
      // reduce across the 16 column-lanes (bits 0..3)
#pragma unroll
      for (int d = 1; d < 16; d <<= 1) s += __shfl_xor(s, d);
      if (l16 == 0) spart[wn][wm * 64 + m * 16 + lq * 4 + r] = s;
    }
  }
  __syncthreads();
  if (tid < BM) {
    int grow = rowBase + tid;
    if (grow < Nrows) scores[grow] = spart[0][tid] + spart[1][tid] + gb2[0];
  }
}

// ---------------------------------------------------------------------------
// Pass 2: per-segment softmax. One block per segment; batch is sorted int32.
// scores -> alpha in place.
// ---------------------------------------------------------------------------
__global__ __launch_bounds__(256) void seg_softmax_kernel(
    const int* __restrict__ batch, float* __restrict__ sc, int Nrows) {
  const int g = blockIdx.x;
  int lo = 0, hi = Nrows;
  while (lo < hi) { int mid = (lo + hi) >> 1; if (batch[mid] < g) lo = mid + 1; else hi = mid; }
  const int start = lo;
  hi = Nrows;
  while (lo < hi) { int mid = (lo + hi) >> 1; if (batch[mid] <= g) lo = mid + 1; else hi = mid; }
  const int end = lo;
  if (start >= end) return;  // empty segment: graph_emb row stays 0

  __shared__ float redm[4], reds[4];
  float mx = -INFINITY;
  for (int i = start + (int)threadIdx.x; i < end; i += 256) mx = fmaxf(mx, sc[i]);
#pragma unroll
  for (int d = 1; d < 64; d <<= 1) mx = fmaxf(mx, __shfl_xor(mx, d));
  if ((threadIdx.x & 63) == 0) redm[threadIdx.x >> 6] = mx;
  __syncthreads();
  mx = fmaxf(fmaxf(redm[0], redm[1]), fmaxf(redm[2], redm[3]));

  float sm = 0.f;
  for (int i = start + (int)threadIdx.x; i < end; i += 256) sm += expf(sc[i] - mx);
#pragma unroll
  for (int d = 1; d < 64; d <<= 1) sm += __shfl_xor(sm, d);
  if ((threadIdx.x & 63) == 0) reds[threadIdx.x >> 6] = sm;
  __syncthreads();
  sm = reds[0] + reds[1] + reds[2] + reds[3];
  const float inv = 1.f / sm;
  for (int i = start + (int)threadIdx.x; i < end; i += 256) sc[i] = expf(sc[i] - mx) * inv;
}

// ---------------------------------------------------------------------------
// Pass 3: feat = relu(x @ feat_w + feat_b); graph_emb[g] += alpha_i * feat_i
// Sorted batch => each 128-row chunk spans few segment runs; aggregate per
// run per column in-wave, one atomicAdd per (run, col).
// ---------------------------------------------------------------------------
__global__ __launch_bounds__(256) void feat_kernel(
    const float* __restrict__ x, const unsigned short* __restrict__ fwt,
    const float* __restrict__ fb, const int* __restrict__ batch,
    const float* __restrict__ alpha, float* __restrict__ gout, int Nrows) {
  __shared__ unsigned short As[BM * BK];
  __shared__ unsigned short Bs[BM * BK];
  __shared__ int seg_l[BM];
  __shared__ float alpha_l[BM];

  const int rowBase = blockIdx.x * BM;
  const int nBase = blockIdx.y * 128;
  const int tid = threadIdx.x;

  if (tid < BM) {
    int grow = rowBase + tid;
    if (grow < Nrows) {
      seg_l[tid] = batch[grow];
      alpha_l[tid] = alpha[grow];
    } else {
      seg_l[tid] = batch[Nrows - 1];
      alpha_l[tid] = 0.f;  // padding rows contribute nothing
    }
  }
  // gemm_core's first __syncthreads() covers seg_l/alpha_l visibility

  const int lane = tid & 63;
  const int wid = tid >> 6;
  const int wm = wid >> 1, wn = wid & 1;
  const int l16 = lane & 15, lq = lane >> 4;

  f32x4 acc[4][4] = {};
  gemm_core(x, fwt, rowBase, nBase, Nrows, As, Bs, acc);

  float fbv[4];
#pragma unroll
  for (int n = 0; n < 4; ++n) fbv[n] = fb[nBase + wn * 64 + n * 16 + l16];

  int sg[4][4];
  float av[4][4];
#pragma unroll
  for (int m = 0; m < 4; ++m)
#pragma unroll
    for (int r = 0; r < 4; ++r) {
      int rl = wm * 64 + m * 16 + lq * 4 + r;
      sg[m][r] = seg_l[rl];
      av[m][r] = alpha_l[rl];
    }
  // weighted feature values, in place
#pragma unroll
  for (int m = 0; m < 4; ++m)
#pragma unroll
    for (int n = 0; n < 4; ++n)
#pragma unroll
      for (int r = 0; r < 4; ++r)
        acc[m][n][r] = av[m][r] * fmaxf(acc[m][n][r] + fbv[n], 0.f);

  const int s0 = seg_l[0], s1 = seg_l[BM - 1];
  for (int s = s0; s <= s1; ++s) {
#pragma unroll
    for (int n = 0; n < 4; ++n) {
      float t = 0.f;
#pragma unroll
      for (int m = 0; m < 4; ++m)
#pragma unroll
        for (int r = 0; r < 4; ++r)
          t += (sg[m][r] == s) ? acc[m][n][r] : 0.f;
      // reduce across the 4 row-groups (lane bits 4,5)
      t += __shfl_xor(t, 16);
      t += __shfl_xor(t, 32);
      if (lq == 0)
        atomicAdd(&gout[(size_t)s * HDIM + nBase + wn * 64 + n * 16 + l16], t);
    }
  }
}

// ---------------------------------------------------------------------------
extern "C" void kernel_launch(void* const* d_in, const int* in_sizes, int n_in,
                              void* d_out, int out_size, void* d_ws, size_t ws_size,
                              hipStream_t stream) {
  const float* x   = (const float*)d_in[0];
  const int* batch = (const int*)d_in[1];
  const float* gw1 = (const float*)d_in[2];
  const float* gb1 = (const float*)d_in[3];
  const float* gw2 = (const float*)d_in[4];
  const float* gb2 = (const float*)d_in[5];
  const float* fw  = (const float*)d_in[6];
  const float* fb  = (const float*)d_in[7];

  float* out = (float*)d_out;
  float* gout = out;                  // [2048 * 256]
  float* alpha = out + NSEG * HDIM;   // [N]  (scores, then alpha in place)
  const int Nrows = in_sizes[0] / HDIM;

  unsigned short* w1t = (unsigned short*)d_ws;        // 128*256 bf16
  unsigned short* fwt = w1t + HGATE * HDIM;           // 256*256 bf16

  hipMemsetAsync(gout, 0, (size_t)NSEG * HDIM * sizeof(float), stream);
  convert_weights_kernel<<<(HDIM * HGATE + HDIM * HDIM + 255) / 256, 256, 0, stream>>>(
      gw1, fw, w1t, fwt);

  const int nChunks = (Nrows + BM - 1) / BM;
  gate_kernel<<<nChunks, 256, 0, stream>>>(x, w1t, gb1, gw2, gb2, alpha, Nrows);
  seg_softmax_kernel<<<NSEG, 256, 0, stream>>>(batch, alpha, Nrows);
  feat_kernel<<<dim3(nChunks, 2), 256, 0, stream>>>(x, fwt, fb, batch, alpha, gout, Nrows);
}

// Round 6
// 862.355 us; speedup vs baseline: 1.0475x; 1.0475x over previous
//
#include <hip/hip_runtime.h>
#include <math.h>

#define NSEG 2048
#define HDIM 256   // H (= K for both GEMMs)
#define HGATE 128  // H/2
#define BM 128
#define BK 64

typedef __attribute__((ext_vector_type(4))) float f32x4;
typedef __attribute__((ext_vector_type(8))) short short8;

static __device__ __forceinline__ unsigned short f2bf(float f) {
  unsigned u = __float_as_uint(f);
  u += 0x7FFFu + ((u >> 16) & 1u);
  return (unsigned short)(u >> 16);
}

// async global->LDS, 16B per lane; LDS dest must be wave-uniform (lane*16 added by HW)
static __device__ __forceinline__ void gload16(const void* g, void* l) {
  __builtin_amdgcn_global_load_lds(
      (const __attribute__((address_space(1))) unsigned int*)g,
      (__attribute__((address_space(3))) unsigned int*)l, 16, 0, 0);
}

// ---------------------------------------------------------------------------
// Weight conversion: fp32 [K][N] -> bf16 transposed [N][K] in workspace.
// ---------------------------------------------------------------------------
__global__ void convert_weights_kernel(const float* __restrict__ w1,
                                       const float* __restrict__ fw,
                                       unsigned short* __restrict__ w1t,
                                       unsigned short* __restrict__ fwt) {
  int i = blockIdx.x * 256 + threadIdx.x;
  if (i < HDIM * HGATE) {
    int k = i >> 7, n = i & (HGATE - 1);
    w1t[n * HDIM + k] = f2bf(w1[i]);
  } else if (i < HDIM * HGATE + HDIM * HDIM) {
    int j = i - HDIM * HGATE;
    int k = j >> 8, n = j & (HDIM - 1);
    fwt[n * HDIM + k] = f2bf(fw[j]);
  }
}

// ---------------------------------------------------------------------------
// x fp32 [N][256] -> bf16 [N][256] in workspace (streaming, 16B stores)
// ---------------------------------------------------------------------------
__global__ __launch_bounds__(256) void convert_x_kernel(
    const float* __restrict__ x, unsigned short* __restrict__ xb, int total16) {
  int i = blockIdx.x * 256 + threadIdx.x;
  const int stride = gridDim.x * 256;
  for (; i < total16; i += stride) {
    const float4* s = (const float4*)(x + (size_t)i * 8);
    float4 v0 = s[0], v1 = s[1];
    union { unsigned short h[8]; uint4 q; } p;
    p.h[0] = f2bf(v0.x); p.h[1] = f2bf(v0.y); p.h[2] = f2bf(v0.z); p.h[3] = f2bf(v0.w);
    p.h[4] = f2bf(v1.x); p.h[5] = f2bf(v1.y); p.h[6] = f2bf(v1.z); p.h[7] = f2bf(v1.w);
    *((uint4*)xb + i) = p.q;
  }
}

// ---------------------------------------------------------------------------
// Pass 1: gate GEMM 128x128 tile, K=256. A,B staged via global_load_lds with
// pre-swizzled global source (LDS stays linear; XOR chunk swizzle on read).
// Epilogue: relu(+b1) . w2 row-reduction -> scores.
// ---------------------------------------------------------------------------
__global__ __launch_bounds__(256) void gate_kernel(
    const unsigned short* __restrict__ xb, const unsigned short* __restrict__ w1t,
    const float* __restrict__ gb1, const float* __restrict__ gw2,
    const float* __restrict__ gb2, float* __restrict__ scores, int Nrows) {
  __shared__ unsigned short As[BM * BK];     // 16 KB
  __shared__ unsigned short Bs[HGATE * BK];  // 16 KB
  __shared__ float spart[2][BM];

  const int rowBase = blockIdx.x * BM;
  const int tid = threadIdx.x;
  const int lane = tid & 63;
  const int wid = tid >> 6;
  const int wm = wid >> 1, wn = wid & 1;
  const int l16 = lane & 15, lq = lane >> 4;
  const int l8r = lane >> 3, l8c = lane & 7;

  f32x4 acc[4][4] = {};

#pragma unroll
  for (int kt = 0; kt < HDIM / BK; ++kt) {
    const int k0 = kt * BK;
    __syncthreads();
    // A tile: 128 rows x 64 bf16; 16 segs of 8 rows; wave handles 4 segs
#pragma unroll
    for (int i = 0; i < 4; ++i) {
      int seg = wid * 4 + i;
      int row = seg * 8 + l8r;
      int gch = l8c ^ (row & 7);
      int grow = rowBase + row; if (grow >= Nrows) grow = Nrows - 1;
      gload16(xb + (size_t)grow * HDIM + k0 + gch * 8, As + seg * 512);
    }
    // B tile: 128 n-rows x 64 bf16
#pragma unroll
    for (int i = 0; i < 4; ++i) {
      int seg = wid * 4 + i;
      int row = seg * 8 + l8r;
      int gch = l8c ^ (row & 7);
      gload16(w1t + (size_t)row * HDIM + k0 + gch * 8, Bs + seg * 512);
    }
    __syncthreads();
#pragma unroll
    for (int kk = 0; kk < 2; ++kk) {
      short8 a[4], b[4];
#pragma unroll
      for (int m = 0; m < 4; ++m) {
        int row = wm * 64 + m * 16 + l16;
        int ck = kk * 4 + lq;
        a[m] = *(const short8*)((const char*)As + row * 128 + ((ck ^ (row & 7)) << 4));
      }
#pragma unroll
      for (int n = 0; n < 4; ++n) {
        int row = wn * 64 + n * 16 + l16;
        int ck = kk * 4 + lq;
        b[n] = *(const short8*)((const char*)Bs + row * 128 + ((ck ^ (row & 7)) << 4));
      }
#pragma unroll
      for (int m = 0; m < 4; ++m)
#pragma unroll
        for (int n = 0; n < 4; ++n)
          acc[m][n] = __builtin_amdgcn_mfma_f32_16x16x32_bf16(a[m], b[n], acc[m][n], 0, 0, 0);
    }
  }

  float b1v[4], w2v[4];
#pragma unroll
  for (int n = 0; n < 4; ++n) {
    int col = wn * 64 + n * 16 + l16;
    b1v[n] = gb1[col];
    w2v[n] = gw2[col];
  }
#pragma unroll
  for (int m = 0; m < 4; ++m) {
#pragma unroll
    for (int r = 0; r < 4; ++r) {
      float s = 0.f;
#pragma unroll
      for (int n = 0; n < 4; ++n)
        s += fmaxf(acc[m][n][r] + b1v[n], 0.f) * w2v[n];
#pragma unroll
      for (int d = 1; d < 16; d <<= 1) s += __shfl_xor(s, d);
      if (l16 == 0) spart[wn][wm * 64 + m * 16 + lq * 4 + r] = s;
    }
  }
  __syncthreads();
  if (tid < BM) {
    int grow = rowBase + tid;
    if (grow < Nrows) scores[grow] = spart[0][tid] + spart[1][tid] + gb2[0];
  }
}

// ---------------------------------------------------------------------------
// Pass 2: per-segment softmax (sorted batch), scores -> alpha in place.
// ---------------------------------------------------------------------------
__global__ __launch_bounds__(256) void seg_softmax_kernel(
    const int* __restrict__ batch, float* __restrict__ sc, int Nrows) {
  const int g = blockIdx.x;
  int lo = 0, hi = Nrows;
  while (lo < hi) { int mid = (lo + hi) >> 1; if (batch[mid] < g) lo = mid + 1; else hi = mid; }
  const int start = lo;
  hi = Nrows;
  while (lo < hi) { int mid = (lo + hi) >> 1; if (batch[mid] <= g) lo = mid + 1; else hi = mid; }
  const int end = lo;
  if (start >= end) return;

  __shared__ float redm[4], reds[4];
  float mx = -INFINITY;
  for (int i = start + (int)threadIdx.x; i < end; i += 256) mx = fmaxf(mx, sc[i]);
#pragma unroll
  for (int d = 1; d < 64; d <<= 1) mx = fmaxf(mx, __shfl_xor(mx, d));
  if ((threadIdx.x & 63) == 0) redm[threadIdx.x >> 6] = mx;
  __syncthreads();
  mx = fmaxf(fmaxf(redm[0], redm[1]), fmaxf(redm[2], redm[3]));

  float sm = 0.f;
  for (int i = start + (int)threadIdx.x; i < end; i += 256) sm += expf(sc[i] - mx);
#pragma unroll
  for (int d = 1; d < 64; d <<= 1) sm += __shfl_xor(sm, d);
  if ((threadIdx.x & 63) == 0) reds[threadIdx.x >> 6] = sm;
  __syncthreads();
  sm = reds[0] + reds[1] + reds[2] + reds[3];
  const float inv = 1.f / sm;
  for (int i = start + (int)threadIdx.x; i < end; i += 256) sc[i] = expf(sc[i] - mx) * inv;
}

// ---------------------------------------------------------------------------
// Pass 3: feat = relu(xb @ fwt^T + fb); graph_emb[g] += alpha_i * feat_i
// 128x256 tile, 8 waves (2x4), single pass over x columns.
// ---------------------------------------------------------------------------
__global__ __launch_bounds__(512) void feat_kernel(
    const unsigned short* __restrict__ xb, const unsigned short* __restrict__ fwt,
    const float* __restrict__ fb, const int* __restrict__ batch,
    const float* __restrict__ alpha, float* __restrict__ gout, int Nrows) {
  __shared__ unsigned short As[BM * BK];    // 16 KB
  __shared__ unsigned short Bs[HDIM * BK];  // 32 KB
  __shared__ int seg_l[BM];
  __shared__ float alpha_l[BM];

  const int rowBase = blockIdx.x * BM;
  const int tid = threadIdx.x;
  const int lane = tid & 63;
  const int wid = tid >> 6;          // 0..7
  const int wm = wid >> 2, wn = wid & 3;
  const int l16 = lane & 15, lq = lane >> 4;
  const int l8r = lane >> 3, l8c = lane & 7;

  if (tid < BM) {
    int grow = rowBase + tid;
    if (grow < Nrows) { seg_l[tid] = batch[grow]; alpha_l[tid] = alpha[grow]; }
    else { seg_l[tid] = batch[Nrows - 1]; alpha_l[tid] = 0.f; }
  }

  f32x4 acc[4][4] = {};
#pragma unroll
  for (int kt = 0; kt < HDIM / BK; ++kt) {
    const int k0 = kt * BK;
    __syncthreads();
    // A: 16 segs, wave handles 2
#pragma unroll
    for (int i = 0; i < 2; ++i) {
      int seg = wid * 2 + i;
      int row = seg * 8 + l8r;
      int gch = l8c ^ (row & 7);
      int grow = rowBase + row; if (grow >= Nrows) grow = Nrows - 1;
      gload16(xb + (size_t)grow * HDIM + k0 + gch * 8, As + seg * 512);
    }
    // B: 256 rows, 32 segs, wave handles 4
#pragma unroll
    for (int i = 0; i < 4; ++i) {
      int seg = wid * 4 + i;
      int row = seg * 8 + l8r;
      int gch = l8c ^ (row & 7);
      gload16(fwt + (size_t)row * HDIM + k0 + gch * 8, Bs + seg * 512);
    }
    __syncthreads();
#pragma unroll
    for (int kk = 0; kk < 2; ++kk) {
      short8 a[4], b[4];
#pragma unroll
      for (int m = 0; m < 4; ++m) {
        int row = wm * 64 + m * 16 + l16;
        int ck = kk * 4 + lq;
        a[m] = *(const short8*)((const char*)As + row * 128 + ((ck ^ (row & 7)) << 4));
      }
#pragma unroll
      for (int n = 0; n < 4; ++n) {
        int row = wn * 64 + n * 16 + l16;
        int ck = kk * 4 + lq;
        b[n] = *(const short8*)((const char*)Bs + row * 128 + ((ck ^ (row & 7)) << 4));
      }
#pragma unroll
      for (int m = 0; m < 4; ++m)
#pragma unroll
        for (int n = 0; n < 4; ++n)
          acc[m][n] = __builtin_amdgcn_mfma_f32_16x16x32_bf16(a[m], b[n], acc[m][n], 0, 0, 0);
    }
  }

  float fbv[4];
#pragma unroll
  for (int n = 0; n < 4; ++n) fbv[n] = fb[wn * 64 + n * 16 + l16];

  int sg[4][4];
  float av[4][4];
#pragma unroll
  for (int m = 0; m < 4; ++m)
#pragma unroll
    for (int r = 0; r < 4; ++r) {
      int rl = wm * 64 + m * 16 + lq * 4 + r;
      sg[m][r] = seg_l[rl];
      av[m][r] = alpha_l[rl];
    }
#pragma unroll
  for (int m = 0; m < 4; ++m)
#pragma unroll
    for (int n = 0; n < 4; ++n)
#pragma unroll
      for (int r = 0; r < 4; ++r)
        acc[m][n][r] = av[m][r] * fmaxf(acc[m][n][r] + fbv[n], 0.f);

  const int s0 = seg_l[0], s1 = seg_l[BM - 1];
  for (int s = s0; s <= s1; ++s) {
#pragma unroll
    for (int n = 0; n < 4; ++n) {
      float t = 0.f;
#pragma unroll
      for (int m = 0; m < 4; ++m)
#pragma unroll
        for (int r = 0; r < 4; ++r)
          t += (sg[m][r] == s) ? acc[m][n][r] : 0.f;
      t += __shfl_xor(t, 16);
      t += __shfl_xor(t, 32);
      if (lq == 0)
        atomicAdd(&gout[(size_t)s * HDIM + wn * 64 + n * 16 + l16], t);
    }
  }
}

// ---------------------------------------------------------------------------
extern "C" void kernel_launch(void* const* d_in, const int* in_sizes, int n_in,
                              void* d_out, int out_size, void* d_ws, size_t ws_size,
                              hipStream_t stream) {
  const float* x   = (const float*)d_in[0];
  const int* batch = (const int*)d_in[1];
  const float* gw1 = (const float*)d_in[2];
  const float* gb1 = (const float*)d_in[3];
  const float* gw2 = (const float*)d_in[4];
  const float* gb2 = (const float*)d_in[5];
  const float* fw  = (const float*)d_in[6];
  const float* fb  = (const float*)d_in[7];

  float* out = (float*)d_out;
  float* gout = out;                  // [2048 * 256]
  float* alpha = out + NSEG * HDIM;   // [N]  (scores, then alpha in place)
  const int Nrows = in_sizes[0] / HDIM;

  unsigned short* w1t = (unsigned short*)d_ws;   // 128*256 bf16
  unsigned short* fwt = w1t + HGATE * HDIM;      // 256*256 bf16
  unsigned short* xb  = fwt + HDIM * HDIM;       // N*256 bf16 (~256 MB)

  hipMemsetAsync(gout, 0, (size_t)NSEG * HDIM * sizeof(float), stream);
  convert_weights_kernel<<<(HDIM * HGATE + HDIM * HDIM + 255) / 256, 256, 0, stream>>>(
      gw1, fw, w1t, fwt);
  const int total16 = in_sizes[0] / 8;
  convert_x_kernel<<<2048, 256, 0, stream>>>(x, xb, total16);

  const int nChunks = (Nrows + BM - 1) / BM;
  gate_kernel<<<nChunks, 256, 0, stream>>>(xb, w1t, gb1, gw2, gb2, alpha, Nrows);
  seg_softmax_kernel<<<NSEG, 256, 0, stream>>>(batch, alpha, Nrows);
  feat_kernel<<<nChunks, 512, 0, stream>>>(xb, fwt, fb, batch, alpha, gout, Nrows);
}

// Round 9
// 820.794 us; speedup vs baseline: 1.1005x; 1.0506x over previous
//
#include <hip/hip_runtime.h>
#include <math.h>

#define NSEG 2048
#define HDIM 256   // H (= K for both GEMMs)
#define HGATE 128  // H/2
#define BM 128
#define BK 64

typedef __attribute__((ext_vector_type(4))) float f32x4;
typedef __attribute__((ext_vector_type(8))) short short8;

static __device__ __forceinline__ unsigned short f2bf(float f) {
  unsigned u = __float_as_uint(f);
  u += 0x7FFFu + ((u >> 16) & 1u);
  return (unsigned short)(u >> 16);
}

// async global->LDS, 16B per lane; LDS dest must be wave-uniform (lane*16 added by HW)
static __device__ __forceinline__ void gload16(const void* g, void* l) {
  __builtin_amdgcn_global_load_lds(
      (const __attribute__((address_space(1))) unsigned int*)g,
      (__attribute__((address_space(3))) unsigned int*)l, 16, 0, 0);
}

// ---------------------------------------------------------------------------
// Weight conversion: fp32 [K][N] -> bf16 transposed [N][K] in workspace.
// ---------------------------------------------------------------------------
__global__ void convert_weights_kernel(const float* __restrict__ w1,
                                       const float* __restrict__ fw,
                                       unsigned short* __restrict__ w1t,
                                       unsigned short* __restrict__ fwt) {
  int i = blockIdx.x * 256 + threadIdx.x;
  if (i < HDIM * HGATE) {
    int k = i >> 7, n = i & (HGATE - 1);
    w1t[n * HDIM + k] = f2bf(w1[i]);
  } else if (i < HDIM * HGATE + HDIM * HDIM) {
    int j = i - HDIM * HGATE;
    int k = j >> 8, n = j & (HDIM - 1);
    fwt[n * HDIM + k] = f2bf(fw[j]);
  }
}

// ---------------------------------------------------------------------------
// Pass 1 (fused): read x fp32, convert->bf16, write xb (byproduct) AND run the
// gate GEMM from the converted LDS tile. B staged via global_load_lds.
// Epilogue: relu(+b1) . w2 row-reduction -> scores.
// Replaces the former standalone convert_x pass (saves one 256 MB read).
// ---------------------------------------------------------------------------
__global__ __launch_bounds__(256) void gateconv_kernel(
    const float* __restrict__ x, const unsigned short* __restrict__ w1t,
    const float* __restrict__ gb1, const float* __restrict__ gw2,
    const float* __restrict__ gb2, unsigned short* __restrict__ xb,
    float* __restrict__ scores, int Nrows) {
  __shared__ unsigned short As[BM * BK];     // 16 KB
  __shared__ unsigned short Bs[HGATE * BK];  // 16 KB
  __shared__ float spart[2][BM];

  const int rowBase = blockIdx.x * BM;
  const int tid = threadIdx.x;
  const int lane = tid & 63;
  const int wid = tid >> 6;
  const int wm = wid >> 1, wn = wid & 1;
  const int l16 = lane & 15, lq = lane >> 4;
  const int l8r = lane >> 3, l8c = lane & 7;

  f32x4 acc[4][4] = {};

#pragma unroll
  for (int kt = 0; kt < HDIM / BK; ++kt) {
    const int k0 = kt * BK;
    __syncthreads();
    // B tile first: async gload_lds, in flight while A converts in VALU
#pragma unroll
    for (int i = 0; i < 4; ++i) {
      int seg = wid * 4 + i;
      int row = seg * 8 + l8r;
      int gch = l8c ^ (row & 7);
      gload16(w1t + (size_t)row * HDIM + k0 + gch * 8, Bs + seg * 512);
    }
    // A tile: 128 rows x 64 cols; 1024 chunks of 8 elems; 4 per thread.
    // fp32 load -> bf16 pack -> swizzled LDS write + linear xb write.
#pragma unroll
    for (int it = 0; it < 4; ++it) {
      int c = tid + it * 256;
      int r = c >> 3, c8 = c & 7;
      int grow = rowBase + r;
      if (grow >= Nrows) grow = Nrows - 1;  // clamp; dup xb writes are identical
      const float* src = x + (size_t)grow * HDIM + k0 + c8 * 8;
      float4 v0 = *(const float4*)src;
      float4 v1 = *(const float4*)(src + 4);
      union { unsigned short h[8]; uint4 q; } p;
      p.h[0] = f2bf(v0.x); p.h[1] = f2bf(v0.y); p.h[2] = f2bf(v0.z); p.h[3] = f2bf(v0.w);
      p.h[4] = f2bf(v1.x); p.h[5] = f2bf(v1.y); p.h[6] = f2bf(v1.z); p.h[7] = f2bf(v1.w);
      *(uint4*)((char*)As + r * 128 + ((c8 ^ (r & 7)) << 4)) = p.q;
      *(uint4*)(xb + (size_t)grow * HDIM + k0 + c8 * 8) = p.q;
    }
    __syncthreads();
#pragma unroll
    for (int kk = 0; kk < 2; ++kk) {
      short8 a[4], b[4];
#pragma unroll
      for (int m = 0; m < 4; ++m) {
        int row = wm * 64 + m * 16 + l16;
        int ck = kk * 4 + lq;
        a[m] = *(const short8*)((const char*)As + row * 128 + ((ck ^ (row & 7)) << 4));
      }
#pragma unroll
      for (int n = 0; n < 4; ++n) {
        int row = wn * 64 + n * 16 + l16;
        int ck = kk * 4 + lq;
        b[n] = *(const short8*)((const char*)Bs + row * 128 + ((ck ^ (row & 7)) << 4));
      }
#pragma unroll
      for (int m = 0; m < 4; ++m)
#pragma unroll
        for (int n = 0; n < 4; ++n)
          acc[m][n] = __builtin_amdgcn_mfma_f32_16x16x32_bf16(a[m], b[n], acc[m][n], 0, 0, 0);
    }
  }

  float b1v[4], w2v[4];
#pragma unroll
  for (int n = 0; n < 4; ++n) {
    int col = wn * 64 + n * 16 + l16;
    b1v[n] = gb1[col];
    w2v[n] = gw2[col];
  }
#pragma unroll
  for (int m = 0; m < 4; ++m) {
#pragma unroll
    for (int r = 0; r < 4; ++r) {
      float s = 0.f;
#pragma unroll
      for (int n = 0; n < 4; ++n)
        s += fmaxf(acc[m][n][r] + b1v[n], 0.f) * w2v[n];
#pragma unroll
      for (int d = 1; d < 16; d <<= 1) s += __shfl_xor(s, d);
      if (l16 == 0) spart[wn][wm * 64 + m * 16 + lq * 4 + r] = s;
    }
  }
  __syncthreads();
  if (tid < BM) {
    int grow = rowBase + tid;
    if (grow < Nrows) scores[grow] = spart[0][tid] + spart[1][tid] + gb2[0];
  }
}

// ---------------------------------------------------------------------------
// Pass 2: per-segment softmax (sorted batch), scores -> alpha in place.
// ---------------------------------------------------------------------------
__global__ __launch_bounds__(256) void seg_softmax_kernel(
    const int* __restrict__ batch, float* __restrict__ sc, int Nrows) {
  const int g = blockIdx.x;
  int lo = 0, hi = Nrows;
  while (lo < hi) { int mid = (lo + hi) >> 1; if (batch[mid] < g) lo = mid + 1; else hi = mid; }
  const int start = lo;
  hi = Nrows;
  while (lo < hi) { int mid = (lo + hi) >> 1; if (batch[mid] <= g) lo = mid + 1; else hi = mid; }
  const int end = lo;
  if (start >= end) return;

  __shared__ float redm[4], reds[4];
  float mx = -INFINITY;
  for (int i = start + (int)threadIdx.x; i < end; i += 256) mx = fmaxf(mx, sc[i]);
#pragma unroll
  for (int d = 1; d < 64; d <<= 1) mx = fmaxf(mx, __shfl_xor(mx, d));
  if ((threadIdx.x & 63) == 0) redm[threadIdx.x >> 6] = mx;
  __syncthreads();
  mx = fmaxf(fmaxf(redm[0], redm[1]), fmaxf(redm[2], redm[3]));

  float sm = 0.f;
  for (int i = start + (int)threadIdx.x; i < end; i += 256) sm += expf(sc[i] - mx);
#pragma unroll
  for (int d = 1; d < 64; d <<= 1) sm += __shfl_xor(sm, d);
  if ((threadIdx.x & 63) == 0) reds[threadIdx.x >> 6] = sm;
  __syncthreads();
  sm = reds[0] + reds[1] + reds[2] + reds[3];
  const float inv = 1.f / sm;
  for (int i = start + (int)threadIdx.x; i < end; i += 256) sc[i] = expf(sc[i] - mx) * inv;
}

// ---------------------------------------------------------------------------
// Pass 3: feat = relu(xb @ fwt^T + fb); graph_emb[g] += alpha_i * feat_i
// 128x256 tile, 8 waves (2x4), single pass over x columns. (unchanged)
// ---------------------------------------------------------------------------
__global__ __launch_bounds__(512) void feat_kernel(
    const unsigned short* __restrict__ xb, const unsigned short* __restrict__ fwt,
    const float* __restrict__ fb, const int* __restrict__ batch,
    const float* __restrict__ alpha, float* __restrict__ gout, int Nrows) {
  __shared__ unsigned short As[BM * BK];    // 16 KB
  __shared__ unsigned short Bs[HDIM * BK];  // 32 KB
  __shared__ int seg_l[BM];
  __shared__ float alpha_l[BM];

  const int rowBase = blockIdx.x * BM;
  const int tid = threadIdx.x;
  const int lane = tid & 63;
  const int wid = tid >> 6;          // 0..7
  const int wm = wid >> 2, wn = wid & 3;
  const int l16 = lane & 15, lq = lane >> 4;
  const int l8r = lane >> 3, l8c = lane & 7;

  if (tid < BM) {
    int grow = rowBase + tid;
    if (grow < Nrows) { seg_l[tid] = batch[grow]; alpha_l[tid] = alpha[grow]; }
    else { seg_l[tid] = batch[Nrows - 1]; alpha_l[tid] = 0.f; }
  }

  f32x4 acc[4][4] = {};
#pragma unroll
  for (int kt = 0; kt < HDIM / BK; ++kt) {
    const int k0 = kt * BK;
    __syncthreads();
    // A: 16 segs, wave handles 2
#pragma unroll
    for (int i = 0; i < 2; ++i) {
      int seg = wid * 2 + i;
      int row = seg * 8 + l8r;
      int gch = l8c ^ (row & 7);
      int grow = rowBase + row; if (grow >= Nrows) grow = Nrows - 1;
      gload16(xb + (size_t)grow * HDIM + k0 + gch * 8, As + seg * 512);
    }
    // B: 256 rows, 32 segs, wave handles 4
#pragma unroll
    for (int i = 0; i < 4; ++i) {
      int seg = wid * 4 + i;
      int row = seg * 8 + l8r;
      int gch = l8c ^ (row & 7);
      gload16(fwt + (size_t)row * HDIM + k0 + gch * 8, Bs + seg * 512);
    }
    __syncthreads();
#pragma unroll
    for (int kk = 0; kk < 2; ++kk) {
      short8 a[4], b[4];
#pragma unroll
      for (int m = 0; m < 4; ++m) {
        int row = wm * 64 + m * 16 + l16;
        int ck = kk * 4 + lq;
        a[m] = *(const short8*)((const char*)As + row * 128 + ((ck ^ (row & 7)) << 4));
      }
#pragma unroll
      for (int n = 0; n < 4; ++n) {
        int row = wn * 64 + n * 16 + l16;
        int ck = kk * 4 + lq;
        b[n] = *(const short8*)((const char*)Bs + row * 128 + ((ck ^ (row & 7)) << 4));
      }
#pragma unroll
      for (int m = 0; m < 4; ++m)
#pragma unroll
        for (int n = 0; n < 4; ++n)
          acc[m][n] = __builtin_amdgcn_mfma_f32_16x16x32_bf16(a[m], b[n], acc[m][n], 0, 0, 0);
    }
  }

  float fbv[4];
#pragma unroll
  for (int n = 0; n < 4; ++n) fbv[n] = fb[wn * 64 + n * 16 + l16];

  int sg[4][4];
  float av[4][4];
#pragma unroll
  for (int m = 0; m < 4; ++m)
#pragma unroll
    for (int r = 0; r < 4; ++r) {
      int rl = wm * 64 + m * 16 + lq * 4 + r;
      sg[m][r] = seg_l[rl];
      av[m][r] = alpha_l[rl];
    }
#pragma unroll
  for (int m = 0; m < 4; ++m)
#pragma unroll
    for (int n = 0; n < 4; ++n)
#pragma unroll
      for (int r = 0; r < 4; ++r)
        acc[m][n][r] = av[m][r] * fmaxf(acc[m][n][r] + fbv[n], 0.f);

  const int s0 = seg_l[0], s1 = seg_l[BM - 1];
  for (int s = s0; s <= s1; ++s) {
#pragma unroll
    for (int n = 0; n < 4; ++n) {
      float t = 0.f;
#pragma unroll
      for (int m = 0; m < 4; ++m)
#pragma unroll
        for (int r = 0; r < 4; ++r)
          t += (sg[m][r] == s) ? acc[m][n][r] : 0.f;
      t += __shfl_xor(t, 16);
      t += __shfl_xor(t, 32);
      if (lq == 0)
        atomicAdd(&gout[(size_t)s * HDIM + wn * 64 + n * 16 + l16], t);
    }
  }
}

// ---------------------------------------------------------------------------
extern "C" void kernel_launch(void* const* d_in, const int* in_sizes, int n_in,
                              void* d_out, int out_size, void* d_ws, size_t ws_size,
                              hipStream_t stream) {
  const float* x   = (const float*)d_in[0];
  const int* batch = (const int*)d_in[1];
  const float* gw1 = (const float*)d_in[2];
  const float* gb1 = (const float*)d_in[3];
  const float* gw2 = (const float*)d_in[4];
  const float* gb2 = (const float*)d_in[5];
  const float* fw  = (const float*)d_in[6];
  const float* fb  = (const float*)d_in[7];

  float* out = (float*)d_out;
  float* gout = out;                  // [2048 * 256]
  float* alpha = out + NSEG * HDIM;   // [N]  (scores, then alpha in place)
  const int Nrows = in_sizes[0] / HDIM;

  unsigned short* w1t = (unsigned short*)d_ws;   // 128*256 bf16
  unsigned short* fwt = w1t + HGATE * HDIM;      // 256*256 bf16
  unsigned short* xb  = fwt + HDIM * HDIM;       // N*256 bf16 (~256 MB)

  hipMemsetAsync(gout, 0, (size_t)NSEG * HDIM * sizeof(float), stream);
  convert_weights_kernel<<<(HDIM * HGATE + HDIM * HDIM + 255) / 256, 256, 0, stream>>>(
      gw1, fw, w1t, fwt);

  const int nChunks = (Nrows + BM - 1) / BM;
  gateconv_kernel<<<nChunks, 256, 0, stream>>>(x, w1t, gb1, gw2, gb2, xb, alpha, Nrows);
  seg_softmax_kernel<<<NSEG, 256, 0, stream>>>(batch, alpha, Nrows);
  feat_kernel<<<nChunks, 512, 0, stream>>>(xb, fwt, fb, batch, alpha, gout, Nrows);
}